// Round 7
// baseline (462.835 us; speedup 1.0000x reference)
//
#include <hip/hip_runtime.h>
#include <math.h>

// Problem constants (match reference setup_inputs)
#define B 32
#define S 4096
#define E 256
#define H 256
#define T 64
#define J (T - 2)
#define NROWS (B * S)        // 131072 rows
#define NBLK (NROWS / 16)    // 8192 blocks: 4 waves/block, 4 rows/wave
#define MAGIC 0x1F2E3D4C5B6A7988ULL

__device__ __forceinline__ float dot4(float4 v, float4 w) {
    return fmaf(v.x, w.x, fmaf(v.y, w.y, fmaf(v.z, w.z, v.w * w.w)));
}

// ONE kernel, ONE graph node.
// Workers: wave wv computes dot(enc[row,:], We) for rows 4wv..4wv+3 (linear
//   whole-grid sweep, 4 independent 1KB loads in flight per wave), lane 0
//   stores float4 to d, block flags completion with a 64-bit MAGIC value
//   (garbage/0xAA-poison cannot alias it -> no init/memset node needed;
//   block 0 resets flags to 0 after use so graph replays stay correct).
// Block 0: after its own rows, polls all flags (relaxed agent loads, 32
//   independent per thread per sweep), one acquire fence, then segment means
//   (8 exclusive segments per thread -> deterministic, no atomics), per-b
//   suffix-LSE scan, mean -> out[0]. Workers never wait: deadlock-free.
__global__ __launch_bounds__(256) void one_kernel(
    const float* __restrict__ enc,
    const int* __restrict__ ends,
    const float* __restrict__ We,
    float* __restrict__ d,
    unsigned long long* __restrict__ flags,
    float* __restrict__ out) {
    const int tid  = threadIdx.x;
    const int lane = tid & 63;
    const int wv   = (blockIdx.x << 2) | (tid >> 6);  // global wave id

    const float4  w4 = reinterpret_cast<const float4*>(We)[lane];
    const float4* p  = reinterpret_cast<const float4*>(enc)
                     + (size_t)wv * 256 + lane;       // 4 rows x 64 float4
    float s0 = dot4(p[0],   w4);
    float s1 = dot4(p[64],  w4);
    float s2 = dot4(p[128], w4);
    float s3 = dot4(p[192], w4);
#pragma unroll
    for (int off = 32; off >= 1; off >>= 1) {
        s0 += __shfl_xor(s0, off, 64);
        s1 += __shfl_xor(s1, off, 64);
        s2 += __shfl_xor(s2, off, 64);
        s3 += __shfl_xor(s3, off, 64);
    }
    if (lane == 0)
        reinterpret_cast<float4*>(d)[wv] = make_float4(s0, s1, s2, s3);

    __syncthreads();
    if (tid == 0) {
        __threadfence();  // release d before flagging
        __hip_atomic_store(&flags[blockIdx.x], MAGIC,
                           __ATOMIC_RELEASE, __HIP_MEMORY_SCOPE_AGENT);
    }
    if (blockIdx.x != 0) return;

    // ---------------- block 0 tail ----------------
    __shared__ int   el[B * T];
    __shared__ float tt[B * T];
    __shared__ float pl[B];

#pragma unroll
    for (int k = 0; k < 8; ++k)
        el[tid + k * 256] = ends[tid + k * 256];  // overlap with poll

    // Poll: sweeps of 32 independent relaxed loads -> ~1 L3 RT per sweep.
    bool all = false;
    while (!all) {
        all = true;
#pragma unroll
        for (int k = 0; k < NBLK / 256; ++k) {
            unsigned long long f = __hip_atomic_load(
                &flags[tid + k * 256], __ATOMIC_RELAXED,
                __HIP_MEMORY_SCOPE_AGENT);
            all = all && (f == MAGIC);
        }
        if (!all) __builtin_amdgcn_s_sleep(8);
    }
    __syncthreads();
    __threadfence();  // acquire: d writes from all XCDs now visible

    // Self-reset flags so the next graph replay starts clean (no memset node).
#pragma unroll
    for (int k = 0; k < NBLK / 256; ++k)
        __hip_atomic_store(&flags[tid + k * 256], 0ULL,
                           __ATOMIC_RELAXED, __HIP_MEMORY_SCOPE_AGENT);

    // Segment means: 8 exclusive segments per thread (contiguous d region).
#pragma unroll
    for (int k = 0; k < 8; ++k) {
        const int g   = tid * 8 + k;       // b*T + tau
        const int tau = g & (T - 1);
        const int b   = g >> 6;
        const int e   = el[g];
        const int st  = (tau == 0) ? 0 : (el[g - 1] + 1);
        const float* db = d + (size_t)b * S;
        float a0 = 0.f, a1 = 0.f, a2 = 0.f, a3 = 0.f;
        int i = st;
        for (; i + 3 <= e; i += 4) {
            a0 += db[i]; a1 += db[i + 1]; a2 += db[i + 2]; a3 += db[i + 3];
        }
        for (; i <= e; ++i) a0 += db[i];
        tt[g] = ((a0 + a1) + (a2 + a3)) / (float)(e - st + 1);
    }
    __syncthreads();

    // Suffix-LSE scan per batch (validated in R4/R6).
    if (tid < B) {
        const float* tb = tt + tid * T;
        float M = tb[T - 1], a = 1.0f, ls = 0.0f;
        for (int j = J - 1; j >= 0; --j) {
            ls += logf(a) + M - tb[j + 2];
            if (j > 0) {
                const float x  = tb[j + 1];
                const float M2 = fmaxf(M, x);
                a = a * __expf(M - M2) + __expf(x - M2);
                M = M2;
            }
        }
        pl[tid] = ls;
    }
    __syncthreads();
    if (tid < 64) {
        float s = (tid < B) ? pl[tid] : 0.0f;
#pragma unroll
        for (int off = 32; off >= 1; off >>= 1)
            s += __shfl_xor(s, off, 64);
        if (tid == 0) out[0] = s / (float)(B * J);
    }
}

extern "C" void kernel_launch(void* const* d_in, const int* in_sizes, int n_in,
                              void* d_out, int out_size, void* d_ws, size_t ws_size,
                              hipStream_t stream) {
    // Inputs: 0 encoder_output (B,S,E) f32; 1 his_turn_end_ids (B,T) i32;
    // 2..5 LSTM weights (algebraically dead); 6 fc_w (1,H+E); 7 fc_b (dead).
    // loss[b,j] = LSE_{m=j+2..T-1}(t[b,m]) - t[b,j+2], t = seg_mean(enc) @ We,
    // We = fc_w[0, H:]. LSTM path and fc_b cancel inside LSE - logits[...,0].
    const float* enc  = (const float*)d_in[0];
    const int*   ends = (const int*)d_in[1];
    const float* We   = (const float*)d_in[6] + H;

    float*              d     = (float*)d_ws;               // 512 KiB
    unsigned long long* flags = (unsigned long long*)((char*)d_ws + (size_t)NROWS * 4);
    float*              out   = (float*)d_out;

    one_kernel<<<NBLK, 256, 0, stream>>>(enc, ends, We, d, flags, out);
}

// Round 8
// 48.285 us; speedup vs baseline: 9.5855x; 9.5855x over previous
//
#include <hip/hip_runtime.h>
#include <math.h>

// Problem constants (match reference setup_inputs)
#define B 32
#define S 4096
#define E 256
#define H 256
#define T 64
#define J (T - 2)
#define NROWS (B * S)  // 131072
#define PAD(i) ((i) + ((i) >> 5))
#define SP (S + (S >> 5))  // padded batch stride in LDS floats

__device__ __forceinline__ float dot4(float4 v, float4 w) {
    return fmaf(v.x, w.x, fmaf(v.y, w.y, fmaf(v.z, w.z, v.w * w.w)));
}

// Kernel 1: streaming row-dot, 4 rows per wave (4 independent 1KB loads in
// flight), linear whole-grid sweep, one float4 store per wave. NO sync, NO
// atomics (R4/R7 lesson: in-kernel cross-block sync costs 100-600us).
__global__ __launch_bounds__(256) void row_dot4_kernel(
    const float* __restrict__ enc,
    const float* __restrict__ We,
    float* __restrict__ d) {
    const int tid  = threadIdx.x;
    const int lane = tid & 63;
    const int wv   = (blockIdx.x << 2) | (tid >> 6);  // global wave id

    const float4  w4 = reinterpret_cast<const float4*>(We)[lane];
    const float4* p  = reinterpret_cast<const float4*>(enc)
                     + (size_t)wv * 256 + lane;       // 4 rows x 64 float4
    float s0 = dot4(p[0],   w4);
    float s1 = dot4(p[64],  w4);
    float s2 = dot4(p[128], w4);
    float s3 = dot4(p[192], w4);
#pragma unroll
    for (int off = 32; off >= 1; off >>= 1) {
        s0 += __shfl_xor(s0, off, 64);
        s1 += __shfl_xor(s1, off, 64);
        s2 += __shfl_xor(s2, off, 64);
        s3 += __shfl_xor(s3, off, 64);
    }
    if (lane == 0)
        reinterpret_cast<float4*>(d)[wv] = make_float4(s0, s1, s2, s3);
}

// Kernel 2: fused tail, ONE block, 1024 threads. Double-buffered LDS staging
// of d in 8 chunks x 4 batches (64KB each, 4 independent float4 loads per
// thread -> latency-pipelined), segment sums from LDS (padded vs stride-64
// bank conflicts), suffix-LSE scan per batch, reduce -> out[0].
__global__ __launch_bounds__(1024) void tail_fused_kernel(
    const float* __restrict__ d,
    const int* __restrict__ ends,
    float* __restrict__ out) {
    const int tid = threadIdx.x;

    __shared__ float ds[2][4 * SP];  // 2 x 67.6 KB
    __shared__ int   el[B * T];      // 8 KB
    __shared__ float tt[B * T];      // 8 KB
    __shared__ float pl[B];

    // ends into LDS (2048 ints).
    el[tid] = ends[tid];
    el[tid + 1024] = ends[tid + 1024];

    // Stage chunk 0 (batches 0..3).
    {
        const float4* dp = reinterpret_cast<const float4*>(d);
        float4 v0 = dp[tid], v1 = dp[tid + 1024],
               v2 = dp[tid + 2048], v3 = dp[tid + 3072];
        float4 vv[4] = {v0, v1, v2, v3};
#pragma unroll
        for (int q = 0; q < 4; ++q) {
            const int idx = tid + q * 1024;       // float4 idx in 4-batch chunk
            const int bl  = idx >> 10;            // local batch 0..3
            const int i   = (idx & 1023) * 4;     // float offset in batch
            float* dst = &ds[0][bl * SP];
            dst[PAD(i)]     = vv[q].x;
            dst[PAD(i + 1)] = vv[q].y;
            dst[PAD(i + 2)] = vv[q].z;
            dst[PAD(i + 3)] = vv[q].w;
        }
    }
    __syncthreads();

    for (int chunk = 0; chunk < 8; ++chunk) {
        const int cur = chunk & 1;

        // Issue next chunk's stage loads + writes BEFORE consuming current
        // (independent buffer -> overlaps with segment sums below the sync).
        if (chunk < 7) {
            const float4* dp = reinterpret_cast<const float4*>(d)
                             + (size_t)(chunk + 1) * 4096;
            float4 v0 = dp[tid], v1 = dp[tid + 1024],
                   v2 = dp[tid + 2048], v3 = dp[tid + 3072];
            float4 vv[4] = {v0, v1, v2, v3};
#pragma unroll
            for (int q = 0; q < 4; ++q) {
                const int idx = tid + q * 1024;
                const int bl  = idx >> 10;
                const int i   = (idx & 1023) * 4;
                float* dst = &ds[cur ^ 1][bl * SP];
                dst[PAD(i)]     = vv[q].x;
                dst[PAD(i + 1)] = vv[q].y;
                dst[PAD(i + 2)] = vv[q].z;
                dst[PAD(i + 3)] = vv[q].w;
            }
        }

        // Segment sums for this chunk's 4 batches (256 segments).
        if (tid < 256) {
            const int bl  = tid >> 6;
            const int tau = tid & 63;
            const int b   = chunk * 4 + bl;
            const int g   = b * T + tau;
            const int e   = el[g];
            const int st  = (tau == 0) ? 0 : (el[g - 1] + 1);
            const float* src = &ds[cur][bl * SP];
            float a0 = 0.f, a1 = 0.f, a2 = 0.f, a3 = 0.f;
            int i = st;
            for (; i + 3 <= e; i += 4) {
                a0 += src[PAD(i)];     a1 += src[PAD(i + 1)];
                a2 += src[PAD(i + 2)]; a3 += src[PAD(i + 3)];
            }
            for (; i <= e; ++i) a0 += src[PAD(i)];
            tt[g] = ((a0 + a1) + (a2 + a3)) / (float)(e - st + 1);
        }
        __syncthreads();
    }

    // Suffix-LSE scan per batch (validated R4/R6 numerics).
    if (tid < B) {
        const float* tb = tt + tid * T;
        float M = tb[T - 1], a = 1.0f, ls = 0.0f;
        for (int j = J - 1; j >= 0; --j) {
            ls += logf(a) + M - tb[j + 2];
            if (j > 0) {
                const float x  = tb[j + 1];
                const float M2 = fmaxf(M, x);
                a = a * __expf(M - M2) + __expf(x - M2);
                M = M2;
            }
        }
        pl[tid] = ls;
    }
    __syncthreads();
    if (tid < 64) {
        float s = (tid < B) ? pl[tid] : 0.0f;
#pragma unroll
        for (int off = 32; off >= 1; off >>= 1)
            s += __shfl_xor(s, off, 64);
        if (tid == 0) out[0] = s / (float)(B * J);
    }
}

extern "C" void kernel_launch(void* const* d_in, const int* in_sizes, int n_in,
                              void* d_out, int out_size, void* d_ws, size_t ws_size,
                              hipStream_t stream) {
    // Inputs: 0 encoder_output (B,S,E) f32; 1 his_turn_end_ids (B,T) i32;
    // 2..5 LSTM weights (algebraically dead); 6 fc_w (1,H+E); 7 fc_b (dead).
    // loss[b,j] = LSE_{m=j+2..T-1}(t[b,m]) - t[b,j+2], t = seg_mean(enc) @ We,
    // We = fc_w[0, H:]. LSTM path and fc_b cancel inside LSE - logits[...,0].
    const float* enc  = (const float*)d_in[0];
    const int*   ends = (const int*)d_in[1];
    const float* We   = (const float*)d_in[6] + H;

    float* d   = (float*)d_ws;   // NROWS floats = 512 KiB
    float* out = (float*)d_out;

    row_dot4_kernel<<<NROWS / 16, 256, 0, stream>>>(enc, We, d);
    tail_fused_kernel<<<1, 1024, 0, stream>>>(d, ends, out);
}

// Round 9
// 37.765 us; speedup vs baseline: 12.2557x; 1.2786x over previous
//
#include <hip/hip_runtime.h>
#include <math.h>

// Problem constants (match reference setup_inputs)
#define B 32
#define S 4096
#define E 256
#define H 256
#define T 64
#define J (T - 2)
#define NROWS (B * S)  // 131072

// Kernel 1 (R3-proven, verbatim): d[row] = dot(enc[row,:], We).
// One 64-lane wave per row; fine-grained linear whole-grid sweep.
__global__ __launch_bounds__(256) void row_dot_kernel(
    const float* __restrict__ enc,
    const float* __restrict__ We,
    float* __restrict__ d) {
    const int gid  = blockIdx.x * blockDim.x + threadIdx.x;
    const int row  = gid >> 6;
    const int lane = threadIdx.x & 63;

    const float4* rowp = reinterpret_cast<const float4*>(enc + (size_t)row * E);
    const float4  v = rowp[lane];
    const float4  w = reinterpret_cast<const float4*>(We)[lane];
    float p = v.x * w.x + v.y * w.y + v.z * w.z + v.w * w.w;

#pragma unroll
    for (int off = 32; off >= 1; off >>= 1)
        p += __shfl_xor(p, off, 64);

    if (lane == 0) d[row] = p;
}

// Kernel 2: one tiny block (1 wave) per segment. t[g] = mean(d[seg g]).
// Coalesced strided read (lane i reads d[st+i], step 64), wave reduce, store.
// 2048 independent blocks -> latency fully overlapped, no LDS, no atomics.
__global__ __launch_bounds__(64) void seg_mean_kernel(
    const float* __restrict__ d,
    const int* __restrict__ ends,
    float* __restrict__ t) {
    const int g    = blockIdx.x;        // b*T + tau
    const int lane = threadIdx.x;
    const int tau  = g & (T - 1);
    const int b    = g >> 6;

    const int e  = ends[g];
    const int st = (tau == 0) ? 0 : (ends[g - 1] + 1);

    const float* db = d + (size_t)b * S;
    float s = 0.0f;
    for (int i = st + lane; i <= e; i += 64) s += db[i];

#pragma unroll
    for (int off = 32; off >= 1; off >>= 1)
        s += __shfl_xor(s, off, 64);

    if (lane == 0) t[g] = s / (float)(e - st + 1);
}

// Kernel 3: one wave. Load all t (8KB) to LDS, lanes 0..31 run the per-batch
// suffix-LSE scan (validated R4/R6), shuffle-reduce, out[0] = mean.
__global__ __launch_bounds__(64) void lse_kernel(
    const float* __restrict__ t,
    float* __restrict__ out) {
    const int lane = threadIdx.x;
    __shared__ float tl[B * T];

    const float4* tp = reinterpret_cast<const float4*>(t);
#pragma unroll
    for (int k = 0; k < 8; ++k) {
        float4 v = tp[lane + k * 64];
        const int i = 4 * (lane + k * 64);
        tl[i] = v.x; tl[i + 1] = v.y; tl[i + 2] = v.z; tl[i + 3] = v.w;
    }
    __syncthreads();

    float ls = 0.0f;
    if (lane < B) {
        const float* tb = tl + lane * T;
        float M = tb[T - 1], a = 1.0f;
        for (int j = J - 1; j >= 0; --j) {
            ls += logf(a) + M - tb[j + 2];
            if (j > 0) {
                const float x  = tb[j + 1];
                const float M2 = fmaxf(M, x);
                a = a * __expf(M - M2) + __expf(x - M2);
                M = M2;
            }
        }
    }

#pragma unroll
    for (int off = 32; off >= 1; off >>= 1)
        ls += __shfl_xor(ls, off, 64);
    if (lane == 0) out[0] = ls / (float)(B * J);
}

extern "C" void kernel_launch(void* const* d_in, const int* in_sizes, int n_in,
                              void* d_out, int out_size, void* d_ws, size_t ws_size,
                              hipStream_t stream) {
    // Inputs: 0 encoder_output (B,S,E) f32; 1 his_turn_end_ids (B,T) i32;
    // 2..5 LSTM weights (algebraically dead); 6 fc_w (1,H+E); 7 fc_b (dead).
    // loss[b,j] = LSE_{m=j+2..T-1}(t[b,m]) - t[b,j+2], t = seg_mean(enc) @ We,
    // We = fc_w[0, H:]. LSTM path and fc_b cancel inside LSE - logits[...,0].
    const float* enc  = (const float*)d_in[0];
    const int*   ends = (const int*)d_in[1];
    const float* We   = (const float*)d_in[6] + H;

    float* d   = (float*)d_ws;               // NROWS floats = 512 KiB
    float* t   = d + NROWS;                  // B*T floats
    float* out = (float*)d_out;

    row_dot_kernel<<<NROWS / 4, 256, 0, stream>>>(enc, We, d);
    seg_mean_kernel<<<B * T, 64, 0, stream>>>(d, ends, t);
    lse_kernel<<<1, 64, 0, stream>>>(t, out);
}

// Round 10
// 35.798 us; speedup vs baseline: 12.9290x; 1.0549x over previous
//
#include <hip/hip_runtime.h>
#include <math.h>

// Problem constants (match reference setup_inputs)
#define B 32
#define S 4096
#define E 256
#define H 256
#define T 64
#define J (T - 2)
#define NROWS (B * S)  // 131072

__device__ __forceinline__ float dot4(float4 v, float4 w) {
    return fmaf(v.x, w.x, fmaf(v.y, w.y, fmaf(v.z, w.z, v.w * w.w)));
}

// Kernel 1: streaming row-dot, 4 contiguous rows per wave.
// 4 independent 1KB loads in flight per wave (vs 1 in R9) -> 4x memory-level
// parallelism; 4 interleaved shuffle-reduce chains; one float4 store; 8192
// blocks (4x fewer dispatches). Proven correct in R8.
__global__ __launch_bounds__(256) void row_dot4_kernel(
    const float* __restrict__ enc,
    const float* __restrict__ We,
    float* __restrict__ d) {
    const int tid  = threadIdx.x;
    const int lane = tid & 63;
    const int wv   = (blockIdx.x << 2) | (tid >> 6);  // global wave id

    const float4  w4 = reinterpret_cast<const float4*>(We)[lane];
    const float4* p  = reinterpret_cast<const float4*>(enc)
                     + (size_t)wv * 256 + lane;       // 4 rows x 64 float4
    float s0 = dot4(p[0],   w4);
    float s1 = dot4(p[64],  w4);
    float s2 = dot4(p[128], w4);
    float s3 = dot4(p[192], w4);
#pragma unroll
    for (int off = 32; off >= 1; off >>= 1) {
        s0 += __shfl_xor(s0, off, 64);
        s1 += __shfl_xor(s1, off, 64);
        s2 += __shfl_xor(s2, off, 64);
        s3 += __shfl_xor(s3, off, 64);
    }
    if (lane == 0)
        reinterpret_cast<float4*>(d)[wv] = make_float4(s0, s1, s2, s3);
}

// Kernel 2 (R9-proven): one 1-wave block per segment. t[g] = mean(d[seg g]).
__global__ __launch_bounds__(64) void seg_mean_kernel(
    const float* __restrict__ d,
    const int* __restrict__ ends,
    float* __restrict__ t) {
    const int g    = blockIdx.x;        // b*T + tau
    const int lane = threadIdx.x;
    const int tau  = g & (T - 1);
    const int b    = g >> 6;

    const int e  = ends[g];
    const int st = (tau == 0) ? 0 : (ends[g - 1] + 1);

    const float* db = d + (size_t)b * S;
    float s = 0.0f;
    for (int i = st + lane; i <= e; i += 64) s += db[i];

#pragma unroll
    for (int off = 32; off >= 1; off >>= 1)
        s += __shfl_xor(s, off, 64);

    if (lane == 0) t[g] = s / (float)(e - st + 1);
}

// Kernel 3 (R9-proven): one wave; per-batch suffix-LSE scan; mean -> out[0].
__global__ __launch_bounds__(64) void lse_kernel(
    const float* __restrict__ t,
    float* __restrict__ out) {
    const int lane = threadIdx.x;
    __shared__ float tl[B * T];

    const float4* tp = reinterpret_cast<const float4*>(t);
#pragma unroll
    for (int k = 0; k < 8; ++k) {
        float4 v = tp[lane + k * 64];
        const int i = 4 * (lane + k * 64);
        tl[i] = v.x; tl[i + 1] = v.y; tl[i + 2] = v.z; tl[i + 3] = v.w;
    }
    __syncthreads();

    float ls = 0.0f;
    if (lane < B) {
        const float* tb = tl + lane * T;
        float M = tb[T - 1], a = 1.0f;
        for (int j = J - 1; j >= 0; --j) {
            ls += logf(a) + M - tb[j + 2];
            if (j > 0) {
                const float x  = tb[j + 1];
                const float M2 = fmaxf(M, x);
                a = a * __expf(M - M2) + __expf(x - M2);
                M = M2;
            }
        }
    }

#pragma unroll
    for (int off = 32; off >= 1; off >>= 1)
        ls += __shfl_xor(ls, off, 64);
    if (lane == 0) out[0] = ls / (float)(B * J);
}

extern "C" void kernel_launch(void* const* d_in, const int* in_sizes, int n_in,
                              void* d_out, int out_size, void* d_ws, size_t ws_size,
                              hipStream_t stream) {
    // Inputs: 0 encoder_output (B,S,E) f32; 1 his_turn_end_ids (B,T) i32;
    // 2..5 LSTM weights (algebraically dead); 6 fc_w (1,H+E); 7 fc_b (dead).
    // loss[b,j] = LSE_{m=j+2..T-1}(t[b,m]) - t[b,j+2], t = seg_mean(enc) @ We,
    // We = fc_w[0, H:]. LSTM path and fc_b cancel inside LSE - logits[...,0].
    const float* enc  = (const float*)d_in[0];
    const int*   ends = (const int*)d_in[1];
    const float* We   = (const float*)d_in[6] + H;

    float* d   = (float*)d_ws;               // NROWS floats = 512 KiB
    float* t   = d + NROWS;                  // B*T floats
    float* out = (float*)d_out;

    row_dot4_kernel<<<NROWS / 16, 256, 0, stream>>>(enc, We, d);
    seg_mean_kernel<<<B * T, 64, 0, stream>>>(d, ends, t);
    lse_kernel<<<1, 64, 0, stream>>>(t, out);
}